// Round 12
// baseline (282.468 us; speedup 1.0000x reference)
//
#include <hip/hip_runtime.h>
#include <stdint.h>

// Problem constants (B=4, N=2048, D=384, heads=6, hd=64)
#define NB 4
#define NN 2048
#define ND 384
#define NH 6
#define HD 64
#define ROWS (NB * NN)  // 8192

typedef int v4i __attribute__((ext_vector_type(4)));
typedef float v4f __attribute__((ext_vector_type(4)));
typedef _Float16 half_t;
typedef half_t v8h __attribute__((ext_vector_type(8)));

// ---------------------------------------------------------------------------
// Kernel 1: fused QKV projection, 128 rows x 64 cols, 8x4 acc/thread, BK=16.
// ROUND-9 VERSION EXACTLY: no register prefetch (prefetch hurt at BK=16 and
// BK=32 -- rounds 10/11). fp32 ascending-k accumulation, bit-identical
// (required: int8 floor boundaries amplify rounding changes -- round 8).
// ---------------------------------------------------------------------------
__global__ __launch_bounds__(256) void qkv_gemm_kernel(
    const float* __restrict__ X,
    const float* __restrict__ Wq, const float* __restrict__ Wk, const float* __restrict__ Wv,
    const float* __restrict__ Bq, const float* __restrict__ Bk, const float* __restrict__ Bv,
    int8_t* __restrict__ Q8, int8_t* __restrict__ K8, int8_t* __restrict__ V8T,
    int* __restrict__ CS)
{
    __shared__ float As[16][132];
    __shared__ float Bs[16][76];
    __shared__ int lcol[64];

    const int t = threadIdx.x;
    const int row0 = blockIdx.x * 128;
    const int c0g = blockIdx.y * 64;
    const int m = c0g / ND;
    const int cl0 = c0g - m * ND;
    const float* W = (m == 0) ? Wq : (m == 1) ? Wk : Wv;
    const float* Bi = (m == 0) ? Bq : (m == 1) ? Bk : Bv;

    const int tx = t & 15;
    const int ty = t >> 4;
    const int lr = t >> 1;
    const int kh = (t & 1) * 8;
    const int rb = t >> 2;
    const int kb = (t & 3) * 4;

    float acc[8][4];
#pragma unroll
    for (int i = 0; i < 8; i++)
#pragma unroll
        for (int j = 0; j < 4; j++) acc[i][j] = 0.f;

    const float* xrow = X + (size_t)(row0 + lr) * ND + kh;
    const float* wrow = W + (size_t)(cl0 + rb) * ND + kb;

    for (int k0 = 0; k0 < ND; k0 += 16) {
        float4 a0 = *(const float4*)(xrow + k0);
        float4 a1 = *(const float4*)(xrow + k0 + 4);
        float4 b0 = *(const float4*)(wrow + k0);
        As[kh + 0][lr] = a0.x; As[kh + 1][lr] = a0.y; As[kh + 2][lr] = a0.z; As[kh + 3][lr] = a0.w;
        As[kh + 4][lr] = a1.x; As[kh + 5][lr] = a1.y; As[kh + 6][lr] = a1.z; As[kh + 7][lr] = a1.w;
        Bs[kb + 0][rb] = b0.x; Bs[kb + 1][rb] = b0.y; Bs[kb + 2][rb] = b0.z; Bs[kb + 3][rb] = b0.w;
        __syncthreads();
#pragma unroll
        for (int kk = 0; kk < 16; kk++) {
            float4 av0 = *(const float4*)&As[kk][ty * 8];
            float4 av1 = *(const float4*)&As[kk][ty * 8 + 4];
            float4 bv  = *(const float4*)&Bs[kk][tx * 4];
            float a[8] = {av0.x, av0.y, av0.z, av0.w, av1.x, av1.y, av1.z, av1.w};
            float b[4] = {bv.x, bv.y, bv.z, bv.w};
#pragma unroll
            for (int i = 0; i < 8; i++)
#pragma unroll
                for (int j = 0; j < 4; j++)
                    acc[i][j] += a[i] * b[j];
        }
        __syncthreads();
    }

    const int bidx = row0 >> 11;
    const int n0 = row0 & 2047;
    const int head = cl0 >> 6;
    if (m == 2) {
        if (t < 64) lcol[t] = 0;
        __syncthreads();
#pragma unroll
        for (int j = 0; j < 4; j++) {
            const int dim = tx * 4 + j;
            const float bias = Bi[cl0 + dim];
            int s = 0;
            uint32_t w[2] = {0u, 0u};
#pragma unroll
            for (int i = 0; i < 8; i++) {
                float v = acc[i][j] + bias;
                int qv = (int)floorf(v * 64.0f);
                qv = max(-128, min(127, qv));
                s += qv;
                w[i >> 2] |= (uint32_t)(qv & 255) << (8 * (i & 3));
            }
            uint32_t* dst = (uint32_t*)(V8T + (((size_t)(bidx * NH + head) * HD + dim) * NN
                                              + n0 + ty * 8));
            dst[0] = w[0];
            dst[1] = w[1];
            atomicAdd(&lcol[dim], s);
        }
        __syncthreads();
        if (t < 64)
            atomicAdd(&CS[(bidx * NH + head) * 64 + t], lcol[t]);
    } else {
        int8_t* Out = (m == 0) ? Q8 : K8;
#pragma unroll
        for (int i = 0; i < 8; i++) {
            const int n = n0 + ty * 8 + i;
            uint32_t w = 0;
#pragma unroll
            for (int j = 0; j < 4; j++) {
                float v = acc[i][j] + Bi[cl0 + tx * 4 + j];
                int qv = (int)floorf(v * 64.0f);
                qv = max(-128, min(127, qv));
                w |= (uint32_t)(qv & 255) << (8 * j);
            }
            *(uint32_t*)(Out + (((size_t)(bidx * NH + head) * NN) + n) * HD + tx * 4) = w;
        }
    }
}

// ---------------------------------------------------------------------------
// Kernel 2: MFMA attention, 256 threads (4 waves) per 16-query strip.
// ROUND-11 VERSION: 4-deep K-frag ring (phase A), 2-deep V-frag ring (phase C).
// ---------------------------------------------------------------------------
__global__ __launch_bounds__(256, 4) void attn_kernel(
    const int8_t* __restrict__ Q8, const int8_t* __restrict__ K8,
    const int8_t* __restrict__ V8T, const int* __restrict__ colsum,
    int8_t* __restrict__ CTX8)
{
    __shared__ int Lp[128 * 68];        // 34816 B packed logits (+pad words)
    __shared__ int gmaxw[128 * 4];      // 2048 B: [g][q] int8
    __shared__ int esumw[128 * 8];      // 4096 B: [g][q] uint16
    // total 40960 B -> 4 blocks/CU

    const int t = threadIdx.x;
    const int wid = t >> 6;
    const int lane = t & 63;
    const int quad = lane >> 4;
    const int l15 = lane & 15;
    const int bh = blockIdx.y;
    const int q0 = blockIdx.x * 16;
    const size_t base = (size_t)bh * NN * HD;
    const v4i zero = {0, 0, 0, 0};

    // ---- Phase A: logits via MFMA, 4-deep K prefetch ring, groups of 4 ----
    v4i afrag = *(const v4i*)(Q8 + base + (size_t)(q0 + l15) * HD + quad * 16);
    {
        const int8_t* kpb = K8 + base + (size_t)(wid * 32 * 16 + l15) * HD + quad * 16;
        v4i kf[4];
#pragma unroll
        for (int i = 0; i < 4; ++i)
            kf[i] = *(const v4i*)(kpb + (size_t)i * 16 * HD);
        const int kt0 = wid * 32;
        for (int g = 0; g < 8; ++g) {
            v4i cur[4] = {kf[0], kf[1], kf[2], kf[3]};
            const int8_t* np = kpb + (size_t)(g + 1) * 4 * 16 * HD;
#pragma unroll
            for (int i = 0; i < 4; ++i)          // prefetch next group (overrun safe)
                kf[i] = *(const v4i*)(np + (size_t)i * 16 * HD);
#pragma unroll
            for (int i = 0; i < 4; ++i) {
                v4i d = __builtin_amdgcn_mfma_i32_16x16x64_i8(afrag, cur[i], zero, 0, 0, 0);
                int e[4];
#pragma unroll
                for (int r = 0; r < 4; ++r) {
                    int lg = (d[r] * 5) >> 12;   // MA=5, SA=12: arith shr == floor
                    e[r] = min(127, max(-128, lg));
                }
                int p01 = __builtin_amdgcn_perm(e[1], e[0], 0x00000400);
                int p23 = __builtin_amdgcn_perm(e[3], e[2], 0x00000400);
                Lp[(kt0 + g * 4 + i) * 68 + quad * 16 + l15] =
                    __builtin_amdgcn_perm(p23, p01, 0x05040100);
            }
        }
    }
    __syncthreads();

    // ---- Phase B1: per-(q,group) max -> gmaxw[g][q] packed bytes ----
#pragma unroll
    for (int it = 0; it < 2; ++it) {
        const int task = t + it * 256;
        const int g = task & 127, qq = task >> 7;
        const int* p = &Lp[g * 68 + qq * 16];
        int wb[16];
#pragma unroll
        for (int a = 0; a < 4; ++a) {
            v4i v = *(const v4i*)&p[a * 4];
            wb[a * 4 + 0] = v.x; wb[a * 4 + 1] = v.y; wb[a * 4 + 2] = v.z; wb[a * 4 + 3] = v.w;
        }
        int mx[4];
#pragma unroll
        for (int b = 0; b < 4; ++b) {
            int m = INT_MIN;
#pragma unroll
            for (int j = 0; j < 16; ++j)
                m = max(m, (int)((unsigned)wb[j] << (8 * (3 - b))));
            mx[b] = m;
        }
        int p01 = __builtin_amdgcn_perm(mx[1], mx[0], 0x00000703);
        int p23 = __builtin_amdgcn_perm(mx[3], mx[2], 0x00000703);
        gmaxw[g * 4 + qq] = __builtin_amdgcn_perm(p23, p01, 0x05040100);
    }
    __syncthreads();

    // ---- Phase B2: prefix max per q row (16 lanes) ----
    if (t < 16) {
        const int wq = t >> 2, bq = 8 * (t & 3);
        int8_t* gb = (int8_t*)gmaxw;
        int m = -128;
        for (int g = 0; g < 128; ++g) {
            int x = (int)(int8_t)(gmaxw[g * 4 + wq] >> bq);
            m = max(m, x);
            gb[g * 16 + t] = (int8_t)m;
        }
    }
    __syncthreads();

    // ---- Phase B3: per-group exp sums vs prefix max -> esumw[g][q] u16 ----
#pragma unroll
    for (int it = 0; it < 2; ++it) {
        const int task = t + it * 256;
        const int g = task & 127, qq = task >> 7;
        const int* p = &Lp[g * 68 + qq * 16];
        int wb[16];
#pragma unroll
        for (int a = 0; a < 4; ++a) {
            v4i v = *(const v4i*)&p[a * 4];
            wb[a * 4 + 0] = v.x; wb[a * 4 + 1] = v.y; wb[a * 4 + 2] = v.z; wb[a * 4 + 3] = v.w;
        }
        const int pw = gmaxw[g * 4 + qq];
        uint32_t sp[2] = {0u, 0u};
#pragma unroll
        for (int b = 0; b < 4; ++b) {
            const int M = (int)(int8_t)(pw >> (8 * b));
            const int cb = 8 - M;
            int s = 0;
#pragma unroll
            for (int j = 0; j < 16; ++j) {
                int x = (int)(int8_t)(wb[j] >> (8 * b));
                int tt = x + cb;                 // <= 8 (x <= prefix max)
                s += (tt >= 0) ? (1 << tt) : 0;
            }
            sp[b >> 1] |= (uint32_t)s << (16 * (b & 1));
        }
        *(int2*)&esumw[g * 8 + qq * 2] = make_int2((int)sp[0], (int)sp[1]);
    }
    __syncthreads();

    // ---- Phase B4: sequential E recurrence (order-dependent, exact) ----
    if (t < 16) {
        const int8_t* gb = (const int8_t*)gmaxw;
        const uint16_t* eb = (const uint16_t*)esumw;
        int E = 0, Mp = -128;
        for (int g = 0; g < 128; ++g) {
            int m = (int)gb[g * 16 + t];
            int d = m - Mp; if (d > 31) d = 31;
            E = (E >> d) + (int)eb[g * 16 + t];
            Mp = m;
        }
        Lp[t * 68 + 64] = 65280 / E;             // inv <= 255 (E >= 256)
        Lp[t * 68 + 65] = Mp;                    // global max
    }
    __syncthreads();

    // ---- Phase C: ctx = (attn-128) . V via MFMA, 2-deep V prefetch ring ----
    const int inv_l = Lp[l15 * 68 + 64];
    const int c24 = 24 - Lp[l15 * 68 + 65];
    const int sh8 = 8 * (l15 & 3);
    v4i accs[4] = {zero, zero, zero, zero};
    const int8_t* vtb = V8T + base;
    const int kc0 = wid * 8;

    v4i bf0[4], bf1[4];
#pragma unroll
    for (int dtb = 0; dtb < 4; ++dtb) {
        bf0[dtb] = *(const v4i*)(vtb + (size_t)(dtb * 16 + l15) * NN + kc0 * 64 + quad * 16);
        bf1[dtb] = *(const v4i*)(vtb + (size_t)(dtb * 16 + l15) * NN + (kc0 + 1) * 64 + quad * 16);
    }
    for (int kc = kc0; kc < kc0 + 8; ++kc) {
        const int* lp = &Lp[(kc * 4 + quad) * 68 + (l15 >> 2) * 16];
        v4i w4[4];
#pragma unroll
        for (int r = 0; r < 4; ++r) w4[r] = *(const v4i*)&lp[4 * r];

        v4i b0 = bf0[0], b1 = bf0[1], b2 = bf0[2], b3 = bf0[3];
#pragma unroll
        for (int dtb = 0; dtb < 4; ++dtb) bf0[dtb] = bf1[dtb];
        const int koffn = (kc + 2) * 64 + quad * 16;     // overrun safe (in d_ws)
#pragma unroll
        for (int dtb = 0; dtb < 4; ++dtb)
            bf1[dtb] = *(const v4i*)(vtb + (size_t)(dtb * 16 + l15) * NN + koffn);

        v4i a;
#pragma unroll
        for (int r = 0; r < 4; ++r) {
            int u[4];
#pragma unroll
            for (int c = 0; c < 4; ++c) {
                int x = (int)(int8_t)(w4[r][c] >> sh8);
                int t1 = x + c24;
                t1 = (t1 < 0) ? 0 : t1;
                u[c] = (int)((unsigned)inv_l << t1);
            }
            int p01 = __builtin_amdgcn_perm(u[1], u[0], 0x00000703);
            int p23 = __builtin_amdgcn_perm(u[3], u[2], 0x00000703);
            a[r] = __builtin_amdgcn_perm(p23, p01, 0x05040100) ^ (int)0x80808080u;
        }
        accs[0] = __builtin_amdgcn_mfma_i32_16x16x64_i8(a, b0, accs[0], 0, 0, 0);
        accs[1] = __builtin_amdgcn_mfma_i32_16x16x64_i8(a, b1, accs[1], 0, 0, 0);
        accs[2] = __builtin_amdgcn_mfma_i32_16x16x64_i8(a, b2, accs[2], 0, 0, 0);
        accs[3] = __builtin_amdgcn_mfma_i32_16x16x64_i8(a, b3, accs[3], 0, 0, 0);
    }
    __syncthreads();                             // Lp dead -> reuse as reduction buf

    // ---- Cross-wave reduction + epilogue (reduction buffer = Lp) ----
    if (wid > 0) {
#pragma unroll
        for (int dt = 0; dt < 4; ++dt)
#pragma unroll
            for (int r = 0; r < 4; ++r)
                Lp[(dt * 4 + r) * 192 + (wid - 1) * 64 + lane] = accs[dt][r];
    }
    __syncthreads();
    if (wid == 0) {
        const int bb = bh / NH, hh = bh % NH;
        const int* cs = &colsum[bh * 64];
#pragma unroll
        for (int dt = 0; dt < 4; ++dt) {
            const int dcol = dt * 16 + l15;
            const int corr = cs[dcol] << 7;      // +128 * colsum
#pragma unroll
            for (int r = 0; r < 4; ++r) {
                const int i = dt * 4 + r;
                int val = accs[dt][r]
                        + Lp[i * 192 + 0 * 64 + lane]
                        + Lp[i * 192 + 1 * 64 + lane]
                        + Lp[i * 192 + 2 * 64 + lane];
                const int q = q0 + quad * 4 + r;
                val = (val + corr) >> 8;         // MAV=1, SAV=8 floor
                val = min(127, max(-128, val));
                CTX8[((size_t)(bb * NN + q)) * ND + hh * HD + dcol] = (int8_t)val;
            }
        }
    }
}

// ---------------------------------------------------------------------------
// Kernel 3: out = requantize(ctx @ wo^T + bo, 256, 7) via f16 MFMA.
// (round-9 version, unchanged; absmax contribution <= 1)
// ---------------------------------------------------------------------------
__global__ __launch_bounds__(256) void out_gemm_kernel(
    const int8_t* __restrict__ CTX8, const float* __restrict__ Wo,
    const float* __restrict__ Bo, float* __restrict__ out)
{
    __shared__ __attribute__((aligned(16))) half_t AH[64 * 40];
    __shared__ __attribute__((aligned(16))) half_t BH[64 * 40];
    __shared__ __attribute__((aligned(16))) half_t BL[64 * 40];

    const int t = threadIdx.x;
    const int wid = t >> 6;
    const int lane = t & 63;
    const int quad = lane >> 4;
    const int l15 = lane & 15;
    const int row0 = blockIdx.x * 64;
    const int c0 = blockIdx.y * 64;

    const int arow = t >> 2;
    const int akb = (t & 3) * 8;
    const int8_t* ap = CTX8 + (size_t)(row0 + arow) * ND + akb;
    const float* wp = Wo + (size_t)(c0 + arow) * ND + akb;

    v4f accH[4], accL[4];
#pragma unroll
    for (int ct = 0; ct < 4; ct++) { accH[ct] = (v4f)0.0f; accL[ct] = (v4f)0.0f; }

    for (int k0 = 0; k0 < ND; k0 += 32) {
        int2 a8 = *(const int2*)(ap + k0);
        float4 w0 = *(const float4*)(wp + k0);
        float4 w1 = *(const float4*)(wp + k0 + 4);
        float wsrc[8] = {w0.x, w0.y, w0.z, w0.w, w1.x, w1.y, w1.z, w1.w};

        __syncthreads();
        v8h av, wh8, wl8;
#pragma unroll
        for (int u = 0; u < 4; u++) {
            av[u]     = (half_t)(float)(int)(int8_t)((a8.x >> (8 * u)) & 0xFF);
            av[4 + u] = (half_t)(float)(int)(int8_t)((a8.y >> (8 * u)) & 0xFF);
        }
#pragma unroll
        for (int u = 0; u < 8; u++) {
            float x = wsrc[u];
            half_t h = (half_t)x;
            wh8[u] = h;
            wl8[u] = (half_t)((x - (float)h) * 2048.0f);
        }
        *(v8h*)&AH[arow * 40 + akb] = av;
        *(v8h*)&BH[arow * 40 + akb] = wh8;
        *(v8h*)&BL[arow * 40 + akb] = wl8;
        __syncthreads();

        v8h af = *(const v8h*)&AH[(wid * 16 + l15) * 40 + quad * 8];
#pragma unroll
        for (int ct = 0; ct < 4; ct++) {
            v8h bh8 = *(const v8h*)&BH[(ct * 16 + l15) * 40 + quad * 8];
            v8h bl8 = *(const v8h*)&BL[(ct * 16 + l15) * 40 + quad * 8];
            accH[ct] = __builtin_amdgcn_mfma_f32_16x16x32_f16(af, bh8, accH[ct], 0, 0, 0);
            accL[ct] = __builtin_amdgcn_mfma_f32_16x16x32_f16(af, bl8, accL[ct], 0, 0, 0);
        }
    }

    const float inv2048 = 4.8828125e-4f;
#pragma unroll
    for (int ct = 0; ct < 4; ct++) {
        const int c = c0 + ct * 16 + l15;
        const float bias = Bo[c];
#pragma unroll
        for (int r = 0; r < 4; r++) {
            const int row = row0 + wid * 16 + quad * 4 + r;
            float v = accH[ct][r] + accL[ct][r] * inv2048 + bias;
            float rq = floorf(v * 2.0f);
            rq = fminf(fmaxf(rq, -128.0f), 127.0f);
            out[(size_t)row * ND + c] = rq;
        }
    }
}

extern "C" void kernel_launch(void* const* d_in, const int* in_sizes, int n_in,
                              void* d_out, int out_size, void* d_ws, size_t ws_size,
                              hipStream_t stream)
{
    const float* x  = (const float*)d_in[0];
    const float* wq = (const float*)d_in[1];
    const float* bq = (const float*)d_in[2];
    const float* wk = (const float*)d_in[3];
    const float* bk = (const float*)d_in[4];
    const float* wv = (const float*)d_in[5];
    const float* bv = (const float*)d_in[6];
    const float* wo = (const float*)d_in[7];
    const float* bo = (const float*)d_in[8];
    float* out = (float*)d_out;

    const size_t MAT = (size_t)ROWS * ND;
    int8_t* Q8  = (int8_t*)d_ws;
    int8_t* K8  = Q8 + MAT;
    int8_t* V8T = K8 + MAT;
    int8_t* C8  = V8T + MAT;
    int*    CS  = (int*)(C8 + MAT);

    hipMemsetAsync(CS, 0, (size_t)NB * NH * 64 * sizeof(int), stream);
    qkv_gemm_kernel<<<dim3(ROWS / 128, 1152 / 64), 256, 0, stream>>>(
        x, wq, wk, wv, bq, bk, bv, Q8, K8, V8T, CS);
    attn_kernel<<<dim3(NN / 16, NB * NH), 256, 0, stream>>>(Q8, K8, V8T, CS, C8);
    out_gemm_kernel<<<dim3(ROWS / 64, ND / 64), 256, 0, stream>>>(C8, wo, bo, out);
}

// Round 13
// 271.546 us; speedup vs baseline: 1.0402x; 1.0402x over previous
//
#include <hip/hip_runtime.h>
#include <stdint.h>

// Problem constants (B=4, N=2048, D=384, heads=6, hd=64)
#define NB 4
#define NN 2048
#define ND 384
#define NH 6
#define HD 64
#define ROWS (NB * NN)  // 8192

typedef int v4i __attribute__((ext_vector_type(4)));
typedef float v4f __attribute__((ext_vector_type(4)));
typedef _Float16 half_t;
typedef half_t v8h __attribute__((ext_vector_type(8)));

// ---------------------------------------------------------------------------
// Kernel 1: fused QKV projection, 128 rows x 64 cols, 8x4 acc/thread, BK=16.
// ROUND-9 VERSION EXACTLY (best measured: 106 us, VGPR 40, occ 31%).
// fp32 ascending-k accumulation, bit-identical (round-8 post-mortem).
// ---------------------------------------------------------------------------
__global__ __launch_bounds__(256) void qkv_gemm_kernel(
    const float* __restrict__ X,
    const float* __restrict__ Wq, const float* __restrict__ Wk, const float* __restrict__ Wv,
    const float* __restrict__ Bq, const float* __restrict__ Bk, const float* __restrict__ Bv,
    int8_t* __restrict__ Q8, int8_t* __restrict__ K8, int8_t* __restrict__ V8T,
    int* __restrict__ CS)
{
    __shared__ float As[16][132];
    __shared__ float Bs[16][76];
    __shared__ int lcol[64];

    const int t = threadIdx.x;
    const int row0 = blockIdx.x * 128;
    const int c0g = blockIdx.y * 64;
    const int m = c0g / ND;
    const int cl0 = c0g - m * ND;
    const float* W = (m == 0) ? Wq : (m == 1) ? Wk : Wv;
    const float* Bi = (m == 0) ? Bq : (m == 1) ? Bk : Bv;

    const int tx = t & 15;
    const int ty = t >> 4;
    const int lr = t >> 1;
    const int kh = (t & 1) * 8;
    const int rb = t >> 2;
    const int kb = (t & 3) * 4;

    float acc[8][4];
#pragma unroll
    for (int i = 0; i < 8; i++)
#pragma unroll
        for (int j = 0; j < 4; j++) acc[i][j] = 0.f;

    const float* xrow = X + (size_t)(row0 + lr) * ND + kh;
    const float* wrow = W + (size_t)(cl0 + rb) * ND + kb;

    for (int k0 = 0; k0 < ND; k0 += 16) {
        float4 a0 = *(const float4*)(xrow + k0);
        float4 a1 = *(const float4*)(xrow + k0 + 4);
        float4 b0 = *(const float4*)(wrow + k0);
        As[kh + 0][lr] = a0.x; As[kh + 1][lr] = a0.y; As[kh + 2][lr] = a0.z; As[kh + 3][lr] = a0.w;
        As[kh + 4][lr] = a1.x; As[kh + 5][lr] = a1.y; As[kh + 6][lr] = a1.z; As[kh + 7][lr] = a1.w;
        Bs[kb + 0][rb] = b0.x; Bs[kb + 1][rb] = b0.y; Bs[kb + 2][rb] = b0.z; Bs[kb + 3][rb] = b0.w;
        __syncthreads();
#pragma unroll
        for (int kk = 0; kk < 16; kk++) {
            float4 av0 = *(const float4*)&As[kk][ty * 8];
            float4 av1 = *(const float4*)&As[kk][ty * 8 + 4];
            float4 bv  = *(const float4*)&Bs[kk][tx * 4];
            float a[8] = {av0.x, av0.y, av0.z, av0.w, av1.x, av1.y, av1.z, av1.w};
            float b[4] = {bv.x, bv.y, bv.z, bv.w};
#pragma unroll
            for (int i = 0; i < 8; i++)
#pragma unroll
                for (int j = 0; j < 4; j++)
                    acc[i][j] += a[i] * b[j];
        }
        __syncthreads();
    }

    const int bidx = row0 >> 11;
    const int n0 = row0 & 2047;
    const int head = cl0 >> 6;
    if (m == 2) {
        if (t < 64) lcol[t] = 0;
        __syncthreads();
#pragma unroll
        for (int j = 0; j < 4; j++) {
            const int dim = tx * 4 + j;
            const float bias = Bi[cl0 + dim];
            int s = 0;
            uint32_t w[2] = {0u, 0u};
#pragma unroll
            for (int i = 0; i < 8; i++) {
                float v = acc[i][j] + bias;
                int qv = (int)floorf(v * 64.0f);
                qv = max(-128, min(127, qv));
                s += qv;
                w[i >> 2] |= (uint32_t)(qv & 255) << (8 * (i & 3));
            }
            uint32_t* dst = (uint32_t*)(V8T + (((size_t)(bidx * NH + head) * HD + dim) * NN
                                              + n0 + ty * 8));
            dst[0] = w[0];
            dst[1] = w[1];
            atomicAdd(&lcol[dim], s);
        }
        __syncthreads();
        if (t < 64)
            atomicAdd(&CS[(bidx * NH + head) * 64 + t], lcol[t]);
    } else {
        int8_t* Out = (m == 0) ? Q8 : K8;
#pragma unroll
        for (int i = 0; i < 8; i++) {
            const int n = n0 + ty * 8 + i;
            uint32_t w = 0;
#pragma unroll
            for (int j = 0; j < 4; j++) {
                float v = acc[i][j] + Bi[cl0 + tx * 4 + j];
                int qv = (int)floorf(v * 64.0f);
                qv = max(-128, min(127, qv));
                w |= (uint32_t)(qv & 255) << (8 * j);
            }
            *(uint32_t*)(Out + (((size_t)(bidx * NH + head) * NN) + n) * HD + tx * 4) = w;
        }
    }
}

// ---------------------------------------------------------------------------
// Kernel 2: MFMA attention, 256 threads (4 waves) per 16-query strip.
// R9 base (1-deep prefetch in A and C) + NEW: B1's logit words carried in
// registers across the B2 barrier so B3 needs no second LDS read pass.
// ---------------------------------------------------------------------------
__global__ __launch_bounds__(256, 4) void attn_kernel(
    const int8_t* __restrict__ Q8, const int8_t* __restrict__ K8,
    const int8_t* __restrict__ V8T, const int* __restrict__ colsum,
    int8_t* __restrict__ CTX8)
{
    __shared__ int Lp[128 * 68];        // 34816 B packed logits (+pad words)
    __shared__ int gmaxw[128 * 4];      // 2048 B: [g][q] int8
    __shared__ int esumw[128 * 8];      // 4096 B: [g][q] uint16
    // total 40960 B -> 4 blocks/CU

    const int t = threadIdx.x;
    const int wid = t >> 6;
    const int lane = t & 63;
    const int quad = lane >> 4;
    const int l15 = lane & 15;
    const int bh = blockIdx.y;
    const int q0 = blockIdx.x * 16;
    const size_t base = (size_t)bh * NN * HD;
    const v4i zero = {0, 0, 0, 0};

    // ---- Phase A: logits via MFMA, K-frag prefetched one kt ahead ----
    v4i afrag = *(const v4i*)(Q8 + base + (size_t)(q0 + l15) * HD + quad * 16);
    {
        const int8_t* kp = K8 + base + (size_t)(wid * 32 * 16 + l15) * HD + quad * 16;
        v4i bfrag = *(const v4i*)kp;
        for (int kt = wid * 32; kt < wid * 32 + 32; ++kt) {
            v4i cur = bfrag;
            kp += 16 * HD;
            bfrag = *(const v4i*)kp;        // prefetch kt+1 (overrun stays in d_ws)
            v4i d = __builtin_amdgcn_mfma_i32_16x16x64_i8(afrag, cur, zero, 0, 0, 0);
            int e[4];
#pragma unroll
            for (int r = 0; r < 4; ++r) {
                int lg = (d[r] * 5) >> 12;      // MA=5, SA=12: arith shr == floor
                e[r] = min(127, max(-128, lg));
            }
            int p01 = __builtin_amdgcn_perm(e[1], e[0], 0x00000400);
            int p23 = __builtin_amdgcn_perm(e[3], e[2], 0x00000400);
            Lp[kt * 68 + quad * 16 + l15] = __builtin_amdgcn_perm(p23, p01, 0x05040100);
        }
    }
    __syncthreads();

    // ---- Phase B1: per-(q,group) max; keep the logit words in registers ----
    int wb[2][16];                      // carried across B2 for reuse in B3
#pragma unroll
    for (int it = 0; it < 2; ++it) {
        const int task = t + it * 256;
        const int g = task & 127, qq = task >> 7;
        const int* p = &Lp[g * 68 + qq * 16];
#pragma unroll
        for (int a = 0; a < 4; ++a) {
            v4i v = *(const v4i*)&p[a * 4];
            wb[it][a * 4 + 0] = v.x; wb[it][a * 4 + 1] = v.y;
            wb[it][a * 4 + 2] = v.z; wb[it][a * 4 + 3] = v.w;
        }
        int mx[4];
#pragma unroll
        for (int b = 0; b < 4; ++b) {
            int m = INT_MIN;
#pragma unroll
            for (int j = 0; j < 16; ++j)
                m = max(m, (int)((unsigned)wb[it][j] << (8 * (3 - b))));
            mx[b] = m;
        }
        int p01 = __builtin_amdgcn_perm(mx[1], mx[0], 0x00000703);
        int p23 = __builtin_amdgcn_perm(mx[3], mx[2], 0x00000703);
        gmaxw[g * 4 + qq] = __builtin_amdgcn_perm(p23, p01, 0x05040100);
    }
    __syncthreads();

    // ---- Phase B2: prefix max per q row (16 lanes) ----
    if (t < 16) {
        const int wq = t >> 2, bq = 8 * (t & 3);
        int8_t* gb = (int8_t*)gmaxw;
        int m = -128;
        for (int g = 0; g < 128; ++g) {
            int x = (int)(int8_t)(gmaxw[g * 4 + wq] >> bq);
            m = max(m, x);
            gb[g * 16 + t] = (int8_t)m;
        }
    }
    __syncthreads();

    // ---- Phase B3: per-group exp sums vs prefix max (wb from registers) ----
#pragma unroll
    for (int it = 0; it < 2; ++it) {
        const int task = t + it * 256;
        const int g = task & 127, qq = task >> 7;
        const int pw = gmaxw[g * 4 + qq];        // 4 prefix maxes (bytes)
        uint32_t sp[2] = {0u, 0u};
#pragma unroll
        for (int b = 0; b < 4; ++b) {
            const int M = (int)(int8_t)(pw >> (8 * b));
            const int cb = 8 - M;
            int s = 0;
#pragma unroll
            for (int j = 0; j < 16; ++j) {
                int x = (int)(int8_t)(wb[it][j] >> (8 * b));
                int tt = x + cb;                 // <= 8 (x <= prefix max)
                s += (tt >= 0) ? (1 << tt) : 0;
            }
            sp[b >> 1] |= (uint32_t)s << (16 * (b & 1));
        }
        *(int2*)&esumw[g * 8 + qq * 2] = make_int2((int)sp[0], (int)sp[1]);
    }
    __syncthreads();

    // ---- Phase B4: sequential E recurrence (order-dependent, exact) ----
    if (t < 16) {
        const int8_t* gb = (const int8_t*)gmaxw;
        const uint16_t* eb = (const uint16_t*)esumw;
        int E = 0, Mp = -128;
        for (int g = 0; g < 128; ++g) {
            int m = (int)gb[g * 16 + t];
            int d = m - Mp; if (d > 31) d = 31;
            E = (E >> d) + (int)eb[g * 16 + t];
            Mp = m;
        }
        Lp[t * 68 + 64] = 65280 / E;             // inv <= 255 (E >= 256)
        Lp[t * 68 + 65] = Mp;                    // global max
    }
    __syncthreads();

    // ---- Phase C: ctx = (attn-128) . V via MFMA, V prefetched one kc ahead ----
    const int inv_l = Lp[l15 * 68 + 64];
    const int c24 = 24 - Lp[l15 * 68 + 65];
    const int sh8 = 8 * (l15 & 3);
    v4i accs[4] = {zero, zero, zero, zero};
    const int8_t* vtb = V8T + base;

    v4i bf[4];
    {
        const int koff0 = wid * 8 * 64 + quad * 16;
#pragma unroll
        for (int dtb = 0; dtb < 4; ++dtb)
            bf[dtb] = *(const v4i*)(vtb + (size_t)(dtb * 16 + l15) * NN + koff0);
    }
    for (int kc = wid * 8; kc < wid * 8 + 8; ++kc) {
        const int* lp = &Lp[(kc * 4 + quad) * 68 + (l15 >> 2) * 16];
        v4i w4[4];
#pragma unroll
        for (int r = 0; r < 4; ++r) w4[r] = *(const v4i*)&lp[4 * r];

        v4i b0 = bf[0], b1 = bf[1], b2 = bf[2], b3 = bf[3];
        const int koffn = (kc + 1) * 64 + quad * 16;     // overrun safe (in d_ws)
#pragma unroll
        for (int dtb = 0; dtb < 4; ++dtb)
            bf[dtb] = *(const v4i*)(vtb + (size_t)(dtb * 16 + l15) * NN + koffn);

        v4i a;
#pragma unroll
        for (int r = 0; r < 4; ++r) {
            int u[4];
#pragma unroll
            for (int c = 0; c < 4; ++c) {
                int x = (int)(int8_t)(w4[r][c] >> sh8);  // raw logit byte (q = l15)
                int t1 = x + c24;                        // 24 - (M - x), <= 24
                t1 = (t1 < 0) ? 0 : t1;
                u[c] = (int)((unsigned)inv_l << t1);     // attn in bits 24..31
            }
            int p01 = __builtin_amdgcn_perm(u[1], u[0], 0x00000703);
            int p23 = __builtin_amdgcn_perm(u[3], u[2], 0x00000703);
            a[r] = __builtin_amdgcn_perm(p23, p01, 0x05040100) ^ (int)0x80808080u;
        }
        accs[0] = __builtin_amdgcn_mfma_i32_16x16x64_i8(a, b0, accs[0], 0, 0, 0);
        accs[1] = __builtin_amdgcn_mfma_i32_16x16x64_i8(a, b1, accs[1], 0, 0, 0);
        accs[2] = __builtin_amdgcn_mfma_i32_16x16x64_i8(a, b2, accs[2], 0, 0, 0);
        accs[3] = __builtin_amdgcn_mfma_i32_16x16x64_i8(a, b3, accs[3], 0, 0, 0);
    }
    __syncthreads();                             // Lp dead -> reuse as reduction buf

    // ---- Cross-wave reduction + epilogue (reduction buffer = Lp) ----
    if (wid > 0) {
#pragma unroll
        for (int dt = 0; dt < 4; ++dt)
#pragma unroll
            for (int r = 0; r < 4; ++r)
                Lp[(dt * 4 + r) * 192 + (wid - 1) * 64 + lane] = accs[dt][r];
    }
    __syncthreads();
    if (wid == 0) {
        const int bb = bh / NH, hh = bh % NH;
        const int* cs = &colsum[bh * 64];
#pragma unroll
        for (int dt = 0; dt < 4; ++dt) {
            const int dcol = dt * 16 + l15;
            const int corr = cs[dcol] << 7;      // +128 * colsum
#pragma unroll
            for (int r = 0; r < 4; ++r) {
                const int i = dt * 4 + r;
                int val = accs[dt][r]
                        + Lp[i * 192 + 0 * 64 + lane]
                        + Lp[i * 192 + 1 * 64 + lane]
                        + Lp[i * 192 + 2 * 64 + lane];
                const int q = q0 + quad * 4 + r;
                val = (val + corr) >> 8;         // MAV=1, SAV=8 floor
                val = min(127, max(-128, val));
                CTX8[((size_t)(bb * NN + q)) * ND + hh * HD + dcol] = (int8_t)val;
            }
        }
    }
}

// ---------------------------------------------------------------------------
// Kernel 3: out = requantize(ctx @ wo^T + bo, 256, 7) via f16 MFMA.
// (round-9 version, unchanged; absmax contribution <= 1)
// ---------------------------------------------------------------------------
__global__ __launch_bounds__(256) void out_gemm_kernel(
    const int8_t* __restrict__ CTX8, const float* __restrict__ Wo,
    const float* __restrict__ Bo, float* __restrict__ out)
{
    __shared__ __attribute__((aligned(16))) half_t AH[64 * 40];
    __shared__ __attribute__((aligned(16))) half_t BH[64 * 40];
    __shared__ __attribute__((aligned(16))) half_t BL[64 * 40];

    const int t = threadIdx.x;
    const int wid = t >> 6;
    const int lane = t & 63;
    const int quad = lane >> 4;
    const int l15 = lane & 15;
    const int row0 = blockIdx.x * 64;
    const int c0 = blockIdx.y * 64;

    const int arow = t >> 2;
    const int akb = (t & 3) * 8;
    const int8_t* ap = CTX8 + (size_t)(row0 + arow) * ND + akb;
    const float* wp = Wo + (size_t)(c0 + arow) * ND + akb;

    v4f accH[4], accL[4];
#pragma unroll
    for (int ct = 0; ct < 4; ct++) { accH[ct] = (v4f)0.0f; accL[ct] = (v4f)0.0f; }

    for (int k0 = 0; k0 < ND; k0 += 32) {
        int2 a8 = *(const int2*)(ap + k0);
        float4 w0 = *(const float4*)(wp + k0);
        float4 w1 = *(const float4*)(wp + k0 + 4);
        float wsrc[8] = {w0.x, w0.y, w0.z, w0.w, w1.x, w1.y, w1.z, w1.w};

        __syncthreads();
        v8h av, wh8, wl8;
#pragma unroll
        for (int u = 0; u < 4; u++) {
            av[u]     = (half_t)(float)(int)(int8_t)((a8.x >> (8 * u)) & 0xFF);
            av[4 + u] = (half_t)(float)(int)(int8_t)((a8.y >> (8 * u)) & 0xFF);
        }
#pragma unroll
        for (int u = 0; u < 8; u++) {
            float x = wsrc[u];
            half_t h = (half_t)x;
            wh8[u] = h;
            wl8[u] = (half_t)((x - (float)h) * 2048.0f);
        }
        *(v8h*)&AH[arow * 40 + akb] = av;
        *(v8h*)&BH[arow * 40 + akb] = wh8;
        *(v8h*)&BL[arow * 40 + akb] = wl8;
        __syncthreads();

        v8h af = *(const v8h*)&AH[(wid * 16 + l15) * 40 + quad * 8];
#pragma unroll
        for (int ct = 0; ct < 4; ct++) {
            v8h bh8 = *(const v8h*)&BH[(ct * 16 + l15) * 40 + quad * 8];
            v8h bl8 = *(const v8h*)&BL[(ct * 16 + l15) * 40 + quad * 8];
            accH[ct] = __builtin_amdgcn_mfma_f32_16x16x32_f16(af, bh8, accH[ct], 0, 0, 0);
            accL[ct] = __builtin_amdgcn_mfma_f32_16x16x32_f16(af, bl8, accL[ct], 0, 0, 0);
        }
    }

    const float inv2048 = 4.8828125e-4f;
#pragma unroll
    for (int ct = 0; ct < 4; ct++) {
        const int c = c0 + ct * 16 + l15;
        const float bias = Bo[c];
#pragma unroll
        for (int r = 0; r < 4; r++) {
            const int row = row0 + wid * 16 + quad * 4 + r;
            float v = accH[ct][r] + accL[ct][r] * inv2048 + bias;
            float rq = floorf(v * 2.0f);
            rq = fminf(fmaxf(rq, -128.0f), 127.0f);
            out[(size_t)row * ND + c] = rq;
        }
    }
}

extern "C" void kernel_launch(void* const* d_in, const int* in_sizes, int n_in,
                              void* d_out, int out_size, void* d_ws, size_t ws_size,
                              hipStream_t stream)
{
    const float* x  = (const float*)d_in[0];
    const float* wq = (const float*)d_in[1];
    const float* bq = (const float*)d_in[2];
    const float* wk = (const float*)d_in[3];
    const float* bk = (const float*)d_in[4];
    const float* wv = (const float*)d_in[5];
    const float* bv = (const float*)d_in[6];
    const float* wo = (const float*)d_in[7];
    const float* bo = (const float*)d_in[8];
    float* out = (float*)d_out;

    const size_t MAT = (size_t)ROWS * ND;
    int8_t* Q8  = (int8_t*)d_ws;
    int8_t* K8  = Q8 + MAT;
    int8_t* V8T = K8 + MAT;
    int8_t* C8  = V8T + MAT;
    int*    CS  = (int*)(C8 + MAT);

    hipMemsetAsync(CS, 0, (size_t)NB * NH * 64 * sizeof(int), stream);
    qkv_gemm_kernel<<<dim3(ROWS / 128, 1152 / 64), 256, 0, stream>>>(
        x, wq, wk, wv, bq, bk, bv, Q8, K8, V8T, CS);
    attn_kernel<<<dim3(NN / 16, NB * NH), 256, 0, stream>>>(Q8, K8, V8T, CS, C8);
    out_gemm_kernel<<<dim3(ROWS / 64, ND / 64), 256, 0, stream>>>(C8, wo, bo, out);
}